// Round 7
// baseline (83.293 us; speedup 1.0000x reference)
//
#include <hip/hip_runtime.h>

#define HID 2048
#define NSLOT 16
#define SLOT_STRIDE 32   // floats; 128 B apart -> distinct cache lines

typedef __attribute__((ext_vector_type(4))) float f32x4;

__device__ __forceinline__ float sigmoidf_(float x) {
    return 1.0f / (1.0f + __expf(-x));
}

// h0 = c0 = 0  =>  W_hh unused, f-gate dead:
//   h[j] = sigmoid(g_o) * tanh( sigmoid(g_i) * tanh(g_g) )
// One 256-thread block per output neuron j; 3 coalesced row streams + x.
template <int K>
__device__ __forceinline__ float neuron_h(
    const float* __restrict__ W,
    const float* __restrict__ b_ih,
    const float* __restrict__ b_hh,
    const float* __restrict__ x,
    float (*red)[4])
{
    const int t    = threadIdx.x;
    const int lane = t & 63;
    const int wv   = t >> 6;
    const int j    = blockIdx.x;

    const float* ri = W + (size_t)j * K;                // i-gate row
    const float* rg = W + (size_t)(j + 2 * HID) * K;    // g-gate row
    const float* ro = W + (size_t)(j + 3 * HID) * K;    // o-gate row

    const float Bi = b_ih[j]           + b_hh[j];
    const float Bg = b_ih[j + 2 * HID] + b_hh[j + 2 * HID];
    const float Bo = b_ih[j + 3 * HID] + b_hh[j + 3 * HID];

    constexpr int U = K / 1024;       // 1 (L0) or 2 (L1/L2)
    f32x4 xv[U], wi[U], wg[U], wo[U];
    #pragma unroll
    for (int u = 0; u < U; ++u) {
        const int off = u * 1024 + t * 4;               // 16B/lane, coalesced
        xv[u] = *reinterpret_cast<const f32x4*>(x  + off);
        wi[u] = *reinterpret_cast<const f32x4*>(ri + off);
        wg[u] = *reinterpret_cast<const f32x4*>(rg + off);
        wo[u] = *reinterpret_cast<const f32x4*>(ro + off);
    }

    float ai = 0.f, ag = 0.f, ao = 0.f;
    #pragma unroll
    for (int u = 0; u < U; ++u) {
        ai = fmaf(wi[u].x, xv[u].x, ai); ai = fmaf(wi[u].y, xv[u].y, ai);
        ai = fmaf(wi[u].z, xv[u].z, ai); ai = fmaf(wi[u].w, xv[u].w, ai);
        ag = fmaf(wg[u].x, xv[u].x, ag); ag = fmaf(wg[u].y, xv[u].y, ag);
        ag = fmaf(wg[u].z, xv[u].z, ag); ag = fmaf(wg[u].w, xv[u].w, ag);
        ao = fmaf(wo[u].x, xv[u].x, ao); ao = fmaf(wo[u].y, xv[u].y, ao);
        ao = fmaf(wo[u].z, xv[u].z, ao); ao = fmaf(wo[u].w, xv[u].w, ao);
    }

    #pragma unroll
    for (int m = 32; m > 0; m >>= 1) {
        ai += __shfl_xor(ai, m, 64);
        ag += __shfl_xor(ag, m, 64);
        ao += __shfl_xor(ao, m, 64);
    }

    if (lane == 0) { red[0][wv] = ai; red[1][wv] = ag; red[2][wv] = ao; }
    __syncthreads();

    const float gi = red[0][0] + red[0][1] + red[0][2] + red[0][3] + Bi;
    const float gg = red[1][0] + red[1][1] + red[1][2] + red[1][3] + Bg;
    const float go = red[2][0] + red[2][1] + red[2][2] + red[2][3] + Bo;
    return sigmoidf_(go) * tanhf(sigmoidf_(gi) * tanhf(gg));
}

template <int K>
__global__ __launch_bounds__(256) void lstm_layer_kernel(
    const float* __restrict__ W,
    const float* __restrict__ b_ih,
    const float* __restrict__ b_hh,
    const float* __restrict__ x,
    float* __restrict__ h_out)
{
    __shared__ float red[3][4];
    const float h = neuron_h<K>(W, b_ih, b_hh, x, red);
    if (threadIdx.x == 0) h_out[blockIdx.x] = h;
}

// Middle layer; also zeroes the FC reduction scratch for the final kernel
// (ordering guaranteed by the dispatch edge).
template <int K>
__global__ __launch_bounds__(256) void lstm_mid_kernel(
    const float* __restrict__ W,
    const float* __restrict__ b_ih,
    const float* __restrict__ b_hh,
    const float* __restrict__ x,
    float* __restrict__ h_out,
    float* __restrict__ slots,        // [NSLOT*SLOT_STRIDE]
    unsigned* __restrict__ cnt,       // [NSLOT*SLOT_STRIDE]
    unsigned* __restrict__ done)      // [1]
{
    __shared__ float red[3][4];
    const float h = neuron_h<K>(W, b_ih, b_hh, x, red);
    if (threadIdx.x == 0) h_out[blockIdx.x] = h;
    if (blockIdx.x == 0) {
        const int t = threadIdx.x;
        if (t < NSLOT) { slots[t * SLOT_STRIDE] = 0.0f; cnt[t * SLOT_STRIDE] = 0u; }
        if (t == NSLOT) done[0] = 0u;
    }
}

// Final layer with fused FC via two-level low-contention reduction:
//   each block: atomicAdd(h[j]*fc_w[j]) into slot (j&15)  [128 adds/slot]
//   per-slot-last block bumps done; overall-last block sums 16 slots -> out.
template <int K>
__global__ __launch_bounds__(256) void lstm_final_kernel(
    const float* __restrict__ W,
    const float* __restrict__ b_ih,
    const float* __restrict__ b_hh,
    const float* __restrict__ x,
    const float* __restrict__ fc_w,   // [HID]
    const float* __restrict__ fc_b,   // [1]
    float* __restrict__ slots,
    unsigned* __restrict__ cnt,
    unsigned* __restrict__ done,
    float* __restrict__ out)          // [1]
{
    __shared__ float red[3][4];
    __shared__ int win;
    const float h = neuron_h<K>(W, b_ih, b_hh, x, red);

    const int t = threadIdx.x;
    const int j = blockIdx.x;

    if (t == 0) {
        const int s = j & (NSLOT - 1);
        float p = h * fc_w[j];
        if (j == 0) p += fc_b[0];                 // fold bias as one contribution
        atomicAdd(&slots[s * SLOT_STRIDE], p);
        __threadfence();                          // slot-add visible before count
        const unsigned r = atomicAdd(&cnt[s * SLOT_STRIDE], 1u);
        int w = 0;
        if (r == (HID / NSLOT - 1)) {             // last contributor to this slot
            const unsigned d = atomicAdd(done, 1u);
            w = (d == NSLOT - 1);                 // last slot overall
        }
        win = w;
    }
    __syncthreads();

    if (win && t < NSLOT) {                       // 16 parallel coherent reads
        float v = atomicAdd(&slots[t * SLOT_STRIDE], 0.0f);
        #pragma unroll
        for (int m = NSLOT / 2; m > 0; m >>= 1) v += __shfl_xor(v, m, 64);
        if (t == 0) out[0] = v;
    }
}

extern "C" void kernel_launch(void* const* d_in, const int* in_sizes, int n_in,
                              void* d_out, int out_size, void* d_ws, size_t ws_size,
                              hipStream_t stream) {
    // setup_inputs() order (all fp32; W_hh_* dead since h0=0):
    // 0:x 1:W_ih_0 2:W_hh_0 3:b_ih_0 4:b_hh_0
    // 5:W_ih_1 6:W_hh_1 7:b_ih_1 8:b_hh_1
    // 9:W_ih_2 10:W_hh_2 11:b_ih_2 12:b_hh_2
    // 13:fc_w 14:fc_b
    const float* x    = (const float*)d_in[0];
    const float* Wih0 = (const float*)d_in[1];
    const float* bih0 = (const float*)d_in[3];
    const float* bhh0 = (const float*)d_in[4];
    const float* Wih1 = (const float*)d_in[5];
    const float* bih1 = (const float*)d_in[7];
    const float* bhh1 = (const float*)d_in[8];
    const float* Wih2 = (const float*)d_in[9];
    const float* bih2 = (const float*)d_in[11];
    const float* bhh2 = (const float*)d_in[12];
    const float* fcw  = (const float*)d_in[13];
    const float* fcb  = (const float*)d_in[14];

    float*    h1    = (float*)d_ws;                    // [HID]
    float*    h2    = h1 + HID;                        // [HID]
    float*    slots = h2 + HID;                        // [NSLOT*SLOT_STRIDE]
    unsigned* cnt   = (unsigned*)(slots + NSLOT * SLOT_STRIDE);
    unsigned* done  = cnt + NSLOT * SLOT_STRIDE;       // [1] (own line)
    float*    out   = (float*)d_out;

    lstm_layer_kernel<1024><<<HID, 256, 0, stream>>>(Wih0, bih0, bhh0, x, h1);
    lstm_mid_kernel<2048><<<HID, 256, 0, stream>>>(Wih1, bih1, bhh1, h1, h2,
                                                   slots, cnt, done);
    lstm_final_kernel<2048><<<HID, 256, 0, stream>>>(Wih2, bih2, bhh2, h2,
                                                     fcw, fcb, slots, cnt, done, out);
}

// Round 8
// 68.059 us; speedup vs baseline: 1.2238x; 1.2238x over previous
//
#include <hip/hip_runtime.h>

#define HID 2048
#define MAGIC 0x5EEDF00Du

typedef __attribute__((ext_vector_type(4))) float f32x4;

__device__ __forceinline__ float sigmoidf_(float x) {
    return 1.0f / (1.0f + __expf(-x));
}

// h0 = c0 = 0  =>  W_hh unused, f-gate dead:
//   h[j] = sigmoid(g_o) * tanh( sigmoid(g_i) * tanh(g_g) )
// One 256-thread block per output neuron j; 3 coalesced row streams + x.
template <int K>
__device__ __forceinline__ float neuron_h(
    const float* __restrict__ W,
    const float* __restrict__ b_ih,
    const float* __restrict__ b_hh,
    const float* __restrict__ x,
    float (*red)[4])
{
    const int t    = threadIdx.x;
    const int lane = t & 63;
    const int wv   = t >> 6;
    const int j    = blockIdx.x;

    const float* ri = W + (size_t)j * K;                // i-gate row
    const float* rg = W + (size_t)(j + 2 * HID) * K;    // g-gate row
    const float* ro = W + (size_t)(j + 3 * HID) * K;    // o-gate row

    const float Bi = b_ih[j]           + b_hh[j];
    const float Bg = b_ih[j + 2 * HID] + b_hh[j + 2 * HID];
    const float Bo = b_ih[j + 3 * HID] + b_hh[j + 3 * HID];

    constexpr int U = K / 1024;       // 1 (L0) or 2 (L1/L2)
    f32x4 xv[U], wi[U], wg[U], wo[U];
    #pragma unroll
    for (int u = 0; u < U; ++u) {
        const int off = u * 1024 + t * 4;               // 16B/lane, coalesced
        xv[u] = *reinterpret_cast<const f32x4*>(x  + off);
        wi[u] = *reinterpret_cast<const f32x4*>(ri + off);
        wg[u] = *reinterpret_cast<const f32x4*>(rg + off);
        wo[u] = *reinterpret_cast<const f32x4*>(ro + off);
    }

    float ai = 0.f, ag = 0.f, ao = 0.f;
    #pragma unroll
    for (int u = 0; u < U; ++u) {
        ai = fmaf(wi[u].x, xv[u].x, ai); ai = fmaf(wi[u].y, xv[u].y, ai);
        ai = fmaf(wi[u].z, xv[u].z, ai); ai = fmaf(wi[u].w, xv[u].w, ai);
        ag = fmaf(wg[u].x, xv[u].x, ag); ag = fmaf(wg[u].y, xv[u].y, ag);
        ag = fmaf(wg[u].z, xv[u].z, ag); ag = fmaf(wg[u].w, xv[u].w, ag);
        ao = fmaf(wo[u].x, xv[u].x, ao); ao = fmaf(wo[u].y, xv[u].y, ao);
        ao = fmaf(wo[u].z, xv[u].z, ao); ao = fmaf(wo[u].w, xv[u].w, ao);
    }

    #pragma unroll
    for (int m = 32; m > 0; m >>= 1) {
        ai += __shfl_xor(ai, m, 64);
        ag += __shfl_xor(ag, m, 64);
        ao += __shfl_xor(ao, m, 64);
    }

    if (lane == 0) { red[0][wv] = ai; red[1][wv] = ag; red[2][wv] = ao; }
    __syncthreads();

    const float gi = red[0][0] + red[0][1] + red[0][2] + red[0][3] + Bi;
    const float gg = red[1][0] + red[1][1] + red[1][2] + red[1][3] + Bg;
    const float go = red[2][0] + red[2][1] + red[2][2] + red[2][3] + Bo;
    return sigmoidf_(go) * tanhf(sigmoidf_(gi) * tanhf(gg));
}

template <int K>
__global__ __launch_bounds__(256) void lstm_layer_kernel(
    const float* __restrict__ W,
    const float* __restrict__ b_ih,
    const float* __restrict__ b_hh,
    const float* __restrict__ x,
    float* __restrict__ h_out)
{
    __shared__ float red[3][4];
    const float h = neuron_h<K>(W, b_ih, b_hh, x, red);
    if (threadIdx.x == 0) h_out[blockIdx.x] = h;
}

// Middle layer; also zeroes the publish flags used by the fused final layer
// (plain stores; visibility guaranteed by the dispatch edge).
template <int K>
__global__ __launch_bounds__(256) void lstm_mid_kernel(
    const float* __restrict__ W,
    const float* __restrict__ b_ih,
    const float* __restrict__ b_hh,
    const float* __restrict__ x,
    float* __restrict__ h_out,
    unsigned long long* __restrict__ flags)   // [HID]
{
    __shared__ float red[3][4];
    const float h = neuron_h<K>(W, b_ih, b_hh, x, red);
    if (threadIdx.x == 0) {
        h_out[blockIdx.x] = h;
        flags[blockIdx.x] = 0ull;             // != MAGIC in high word
    }
}

// Final layer with fused FC, no RMW atomics / fences:
//   blocks 0..HID-1: compute h, publish u64{lo=f32(h*fc_w[j]), hi=MAGIC}
//                    with one agent-scope RELEASE store.
//   block HID (poller): acquire-load all HID flags until MAGIC, sum payloads
//                    in a fixed order, add fc_b, store out[0].
template <int K>
__global__ __launch_bounds__(256) void lstm_final_fused(
    const float* __restrict__ W,
    const float* __restrict__ b_ih,
    const float* __restrict__ b_hh,
    const float* __restrict__ x,
    const float* __restrict__ fc_w,   // [HID]
    const float* __restrict__ fc_b,   // [1]
    unsigned long long* __restrict__ flags,   // [HID]
    float* __restrict__ out)          // [1]
{
    const int t    = threadIdx.x;
    const int lane = t & 63;
    const int wv   = t >> 6;

    if (blockIdx.x == HID) {          // ---- poller block ----
        float sum = 0.f;
        #pragma unroll
        for (int c = 0; c < HID / 256; ++c) {
            const int s = c * 256 + t;
            unsigned long long v;
            do {
                v = __hip_atomic_load(&flags[s], __ATOMIC_ACQUIRE,
                                      __HIP_MEMORY_SCOPE_AGENT);
            } while ((unsigned)(v >> 32) != MAGIC);
            union { unsigned u; float f; } p;
            p.u = (unsigned)v;
            sum += p.f;
        }
        #pragma unroll
        for (int m = 32; m > 0; m >>= 1) sum += __shfl_xor(sum, m, 64);
        __shared__ float fred[4];
        if (lane == 0) fred[wv] = sum;
        __syncthreads();
        if (t == 0) out[0] = fred[0] + fred[1] + fred[2] + fred[3] + fc_b[0];
        return;
    }

    __shared__ float red[3][4];
    const float h = neuron_h<K>(W, b_ih, b_hh, x, red);
    if (t == 0) {
        union { unsigned u; float f; } p;
        p.f = h * fc_w[blockIdx.x];
        const unsigned long long v =
            ((unsigned long long)MAGIC << 32) | (unsigned long long)p.u;
        __hip_atomic_store(&flags[blockIdx.x], v, __ATOMIC_RELEASE,
                           __HIP_MEMORY_SCOPE_AGENT);
    }
}

extern "C" void kernel_launch(void* const* d_in, const int* in_sizes, int n_in,
                              void* d_out, int out_size, void* d_ws, size_t ws_size,
                              hipStream_t stream) {
    // setup_inputs() order (all fp32; W_hh_* dead since h0=0):
    // 0:x 1:W_ih_0 2:W_hh_0 3:b_ih_0 4:b_hh_0
    // 5:W_ih_1 6:W_hh_1 7:b_ih_1 8:b_hh_1
    // 9:W_ih_2 10:W_hh_2 11:b_ih_2 12:b_hh_2
    // 13:fc_w 14:fc_b
    const float* x    = (const float*)d_in[0];
    const float* Wih0 = (const float*)d_in[1];
    const float* bih0 = (const float*)d_in[3];
    const float* bhh0 = (const float*)d_in[4];
    const float* Wih1 = (const float*)d_in[5];
    const float* bih1 = (const float*)d_in[7];
    const float* bhh1 = (const float*)d_in[8];
    const float* Wih2 = (const float*)d_in[9];
    const float* bih2 = (const float*)d_in[11];
    const float* bhh2 = (const float*)d_in[12];
    const float* fcw  = (const float*)d_in[13];
    const float* fcb  = (const float*)d_in[14];

    float* h1 = (float*)d_ws;                          // [HID]
    float* h2 = h1 + HID;                              // [HID]
    unsigned long long* flags =
        (unsigned long long*)(h2 + HID);               // [HID], 8B-aligned
    float* out = (float*)d_out;

    lstm_layer_kernel<1024><<<HID, 256, 0, stream>>>(Wih0, bih0, bhh0, x, h1);
    lstm_mid_kernel<2048><<<HID, 256, 0, stream>>>(Wih1, bih1, bhh1, h1, h2, flags);
    lstm_final_fused<2048><<<HID + 1, 256, 0, stream>>>(Wih2, bih2, bhh2, h2,
                                                        fcw, fcb, flags, out);
}

// Round 9
// 32.595 us; speedup vs baseline: 2.5554x; 2.0880x over previous
//
#include <hip/hip_runtime.h>

#define HID 2048

typedef __attribute__((ext_vector_type(4))) float f32x4;
typedef __attribute__((ext_vector_type(2))) float f32x2;

__device__ __forceinline__ float sigmoidf_(float x) {
    return 1.0f / (1.0f + __expf(-x));
}

// h0 = c0 = 0  =>  W_hh unused, f-gate dead:
//   h[j] = sigmoid(g_o) * tanh( sigmoid(g_i) * tanh(g_g) )
// 512-thread block computes TWO neurons (j0, j0+1): 6 coalesced row streams + x.
// K=1024 -> 8B/lane (f32x2); K=2048 -> 16B/lane (f32x4).
template <int K>
__global__ __launch_bounds__(512) void lstm_layer_kernel(
    const float* __restrict__ W,     // [4*HID, K] fp32
    const float* __restrict__ b_ih,  // [4*HID] fp32
    const float* __restrict__ b_hh,  // [4*HID] fp32
    const float* __restrict__ x,     // [K] fp32
    float* __restrict__ h_out)       // [HID] fp32
{
    const int t    = threadIdx.x;
    const int lane = t & 63;
    const int wv   = t >> 6;                       // 0..7
    const int j0   = blockIdx.x * 2;

    const float* rp[6];
    rp[0] = W + (size_t)j0 * K;                    // n0 i-gate
    rp[1] = W + (size_t)(j0 + 2 * HID) * K;        // n0 g-gate
    rp[2] = W + (size_t)(j0 + 3 * HID) * K;        // n0 o-gate
    rp[3] = W + (size_t)(j0 + 1) * K;              // n1 i-gate
    rp[4] = W + (size_t)(j0 + 1 + 2 * HID) * K;    // n1 g-gate
    rp[5] = W + (size_t)(j0 + 1 + 3 * HID) * K;    // n1 o-gate

    constexpr int VW = K / 512;                    // 2 (L0) or 4 (L1/L2)
    const int off = t * VW;

    float acc[6] = {0.f, 0.f, 0.f, 0.f, 0.f, 0.f};

    if constexpr (VW == 4) {
        f32x4 xv = *reinterpret_cast<const f32x4*>(x + off);
        #pragma unroll
        for (int r = 0; r < 6; ++r) {
            f32x4 w = *reinterpret_cast<const f32x4*>(rp[r] + off);
            acc[r] = fmaf(w.x, xv.x, acc[r]);
            acc[r] = fmaf(w.y, xv.y, acc[r]);
            acc[r] = fmaf(w.z, xv.z, acc[r]);
            acc[r] = fmaf(w.w, xv.w, acc[r]);
        }
    } else {
        f32x2 xv = *reinterpret_cast<const f32x2*>(x + off);
        #pragma unroll
        for (int r = 0; r < 6; ++r) {
            f32x2 w = *reinterpret_cast<const f32x2*>(rp[r] + off);
            acc[r] = fmaf(w.x, xv.x, acc[r]);
            acc[r] = fmaf(w.y, xv.y, acc[r]);
        }
    }

    #pragma unroll
    for (int m = 32; m > 0; m >>= 1) {
        #pragma unroll
        for (int r = 0; r < 6; ++r) acc[r] += __shfl_xor(acc[r], m, 64);
    }

    __shared__ float red[6][8];
    if (lane == 0) {
        #pragma unroll
        for (int r = 0; r < 6; ++r) red[r][wv] = acc[r];
    }
    __syncthreads();

    if (t < 2) {                                   // thread t finalizes neuron j0+t
        const int j = j0 + t;
        const int b = t * 3;
        float gi = b_ih[j]           + b_hh[j];
        float gg = b_ih[j + 2 * HID] + b_hh[j + 2 * HID];
        float go = b_ih[j + 3 * HID] + b_hh[j + 3 * HID];
        #pragma unroll
        for (int w = 0; w < 8; ++w) {
            gi += red[b + 0][w];
            gg += red[b + 1][w];
            go += red[b + 2][w];
        }
        h_out[j] = sigmoidf_(go) * tanhf(sigmoidf_(gi) * tanhf(gg));
    }
}

// out[0] = dot(fc_w, h) + fc_b  (OUT_DIM == 1): one wave, pure in-wave reduce.
__global__ __launch_bounds__(64) void fc_kernel(
    const float* __restrict__ fc_w,  // [HID]
    const float* __restrict__ fc_b,  // [1]
    const float* __restrict__ h,     // [HID]
    float* __restrict__ out)         // [1]
{
    const int t = threadIdx.x;
    float acc = 0.f;
    #pragma unroll
    for (int c = 0; c < HID / 256; ++c) {          // 8 chunks of 256 floats
        const int off = c * 256 + t * 4;
        f32x4 w  = *reinterpret_cast<const f32x4*>(fc_w + off);
        f32x4 hv = *reinterpret_cast<const f32x4*>(h    + off);
        acc = fmaf(w.x, hv.x, acc); acc = fmaf(w.y, hv.y, acc);
        acc = fmaf(w.z, hv.z, acc); acc = fmaf(w.w, hv.w, acc);
    }
    #pragma unroll
    for (int m = 32; m > 0; m >>= 1) acc += __shfl_xor(acc, m, 64);
    if (t == 0) out[0] = acc + fc_b[0];
}

extern "C" void kernel_launch(void* const* d_in, const int* in_sizes, int n_in,
                              void* d_out, int out_size, void* d_ws, size_t ws_size,
                              hipStream_t stream) {
    // setup_inputs() order (all fp32; W_hh_* dead since h0=0):
    // 0:x 1:W_ih_0 2:W_hh_0 3:b_ih_0 4:b_hh_0
    // 5:W_ih_1 6:W_hh_1 7:b_ih_1 8:b_hh_1
    // 9:W_ih_2 10:W_hh_2 11:b_ih_2 12:b_hh_2
    // 13:fc_w 14:fc_b
    const float* x    = (const float*)d_in[0];
    const float* Wih0 = (const float*)d_in[1];
    const float* bih0 = (const float*)d_in[3];
    const float* bhh0 = (const float*)d_in[4];
    const float* Wih1 = (const float*)d_in[5];
    const float* bih1 = (const float*)d_in[7];
    const float* bhh1 = (const float*)d_in[8];
    const float* Wih2 = (const float*)d_in[9];
    const float* bih2 = (const float*)d_in[11];
    const float* bhh2 = (const float*)d_in[12];
    const float* fcw  = (const float*)d_in[13];
    const float* fcb  = (const float*)d_in[14];

    float* h1 = (float*)d_ws;        // [HID] fp32
    float* h2 = h1 + HID;
    float* h3 = h2 + HID;

    lstm_layer_kernel<1024><<<HID / 2, 512, 0, stream>>>(Wih0, bih0, bhh0, x,  h1);
    lstm_layer_kernel<2048><<<HID / 2, 512, 0, stream>>>(Wih1, bih1, bhh1, h1, h2);
    lstm_layer_kernel<2048><<<HID / 2, 512, 0, stream>>>(Wih2, bih2, bhh2, h2, h3);
    fc_kernel<<<1, 64, 0, stream>>>(fcw, fcb, h3, (float*)d_out);
}